// Round 13
// baseline (274.760 us; speedup 1.0000x reference)
//
#include <hip/hip_runtime.h>
#include <hip/hip_bf16.h>
#include <math.h>

#define N_NODES 100000
#define N_EDGES 3200000
#define IN_FEAT 256
#define OUT_FEAT 128
#define ALPHA 0.2f
#define NB 782       // ceil(100000/128) buckets of 128 rows
#define NBLK 200     // partition blocks
#define CHUNK 16000  // edges per partition block (200*16000 = 3.2M exact)

#define SCAN_N (NB * NBLK)  // 156400
#define SCAN_ELEMS 2048     // per block (256 thr x 8)
#define SCAN_BLOCKS ((SCAN_N + SCAN_ELEMS - 1) / SCAN_ELEMS)  // 77
#define SCAT_IT 10          // per-thread register staging (512 thr x 10 = 5120)

typedef __attribute__((ext_vector_type(8))) short short8;
typedef __attribute__((ext_vector_type(4))) float f32x4;

__device__ __forceinline__ ushort f2bf(float f) {
  __hip_bfloat16 h = __float2bfloat16(f);
  return __builtin_bit_cast(ushort, h);
}
__device__ __forceinline__ float bflo(uint u) { return __uint_as_float(u << 16); }
__device__ __forceinline__ float bfhi(uint u) { return __uint_as_float(u & 0xFFFF0000u); }

__device__ __forceinline__ short8 pack_bf8(float4 a, float4 b) {
  union { short8 s; uint u[4]; } r;
  r.u[0] = (uint)f2bf(a.x) | ((uint)f2bf(a.y) << 16);
  r.u[1] = (uint)f2bf(a.z) | ((uint)f2bf(a.w) << 16);
  r.u[2] = (uint)f2bf(b.x) | ((uint)f2bf(b.y) << 16);
  r.u[3] = (uint)f2bf(b.z) | ((uint)f2bf(b.w) << 16);
  return r.s;
}

// ---------------- W transpose + bf16 cast: Wt[c][k] = bf16(W[k][c]) ----------------
__global__ __launch_bounds__(256) void wt_kernel(const float* __restrict__ W,
                                                 ushort* __restrict__ Wt) {
  int id = blockIdx.x * 256 + threadIdx.x;
  int c = id >> 8;
  int k = id & 255;
  Wt[id] = f2bf(W[k * OUT_FEAT + c]);
}

// ---------------- fused: hist (blocks 0..199) + gemm h16 (blocks 200..981) ----------------
// gemm: B (all of Wt) resident in LDS, A direct from global -> ZERO barriers in K-loop.
#define GBM 128
#define GBK 32
#define B_LD 264   // 256 + 8 pad: (col*132)%32 spreads rows over banks, <=2-way conflict
#define C_LD 136
#define HIST_BLKS NBLK

__global__ __launch_bounds__(256) void gemm_hist_kernel(const float* __restrict__ x,
                                                        const ushort* __restrict__ Wt,
                                                        const float* __restrict__ a,
                                                        const int* __restrict__ erow,
                                                        ushort* __restrict__ h16,
                                                        float* __restrict__ s_src,
                                                        float* __restrict__ s_dst,
                                                        int* __restrict__ G) {
  __shared__ union {
    ushort B[OUT_FEAT * B_LD];  // 67584 B
    ushort C[GBM * C_LD];       // 34816 B (aliases B after K-loop)
    int hist[NB];
  } sm;
  __shared__ float sa[2 * OUT_FEAT];
  const int tid = threadIdx.x;

  if (blockIdx.x < HIST_BLKS) {
    // ---------- per-(block,bucket) histogram, LDS atomics only ----------
    const int b = blockIdx.x;
    for (int k = tid; k < NB; k += 256) sm.hist[k] = 0;
    __syncthreads();
    const int base = b * CHUNK;
    for (int i = base + tid; i < base + CHUNK; i += 256) atomicAdd(&sm.hist[erow[i] >> 7], 1);
    __syncthreads();
    for (int k = tid; k < NB; k += 256) G[k * NBLK + b] = sm.hist[k];
    return;
  }

  // ---------- gemm path ----------
  const int row0 = (blockIdx.x - HIST_BLKS) * GBM;
  const int lane = tid & 63;
  const int wave = tid >> 6;
  const int lr = lane & 15;
  const int lg = lane >> 4;

  sa[tid] = a[tid];  // 256 threads == 2*OUT_FEAT; visible after first barrier

  // load ALL of Wt into LDS once (4096 short8 chunks by 256 threads)
  for (int i = tid; i < (OUT_FEAT * IN_FEAT) / 8; i += 256) {
    int col = i >> 5;
    int kc = (i & 31) << 3;
    *(short8*)&sm.B[col * B_LD + kc] = *(const short8*)(Wt + col * IN_FEAT + kc);
  }
  __syncthreads();

  f32x4 acc[2][8];
#pragma unroll
  for (int m = 0; m < 2; ++m)
#pragma unroll
    for (int n = 0; n < 8; ++n) acc[m][n] = (f32x4)(0.f);

  const int arow0 = row0 + wave * 32 + lr;
  const int arow1 = arow0 + 16;
  const float* xg0 = x + (size_t)arow0 * IN_FEAT + lg * 8;
  const float* xg1 = x + (size_t)arow1 * IN_FEAT + lg * 8;
  const bool ok0 = arow0 < N_NODES;
  const bool ok1 = arow1 < N_NODES;
  const float4 z4 = make_float4(0.f, 0.f, 0.f, 0.f);

#pragma unroll
  for (int ks = 0; ks < IN_FEAT / GBK; ++ks) {
    float4 a0 = ok0 ? *(const float4*)(xg0 + ks * GBK) : z4;
    float4 a1 = ok0 ? *(const float4*)(xg0 + ks * GBK + 4) : z4;
    float4 b0 = ok1 ? *(const float4*)(xg1 + ks * GBK) : z4;
    float4 b1 = ok1 ? *(const float4*)(xg1 + ks * GBK + 4) : z4;
    short8 af0 = pack_bf8(a0, a1);
    short8 af1 = pack_bf8(b0, b1);
    short8 bf[8];
#pragma unroll
    for (int n = 0; n < 8; ++n)
      bf[n] = *(const short8*)&sm.B[(n * 16 + lr) * B_LD + ks * GBK + lg * 8];
#pragma unroll
    for (int n = 0; n < 8; ++n) {
      acc[0][n] = __builtin_amdgcn_mfma_f32_16x16x32_bf16(af0, bf[n], acc[0][n], 0, 0, 0);
      acc[1][n] = __builtin_amdgcn_mfma_f32_16x16x32_bf16(af1, bf[n], acc[1][n], 0, 0, 0);
    }
  }

  __syncthreads();  // all waves done reading B before C aliases it
#pragma unroll
  for (int m = 0; m < 2; ++m)
#pragma unroll
    for (int n = 0; n < 8; ++n)
#pragma unroll
      for (int i = 0; i < 4; ++i)
        sm.C[(wave * 32 + m * 16 + lg * 4 + i) * C_LD + n * 16 + lr] = f2bf(acc[m][n][i]);
  __syncthreads();
  {
    const int row = tid >> 1;
    const int sh = tid & 1;
    const bool ok = (row0 + row) < N_NODES;
    const ushort* src = &sm.C[row * C_LD + sh * 64];
    if (ok) {
      ushort* dst = h16 + (size_t)(row0 + row) * OUT_FEAT + sh * 64;
#pragma unroll
      for (int i = 0; i < 8; ++i) *(short8*)(dst + i * 8) = *(const short8*)(src + i * 8);
    }
    // fused s_src/s_dst: dot(h_row, a_src), dot(h_row, a_dst)
    float ds = 0.f, dd = 0.f;
    const float* as = &sa[sh * 64];
    const float* ad = &sa[OUT_FEAT + sh * 64];
#pragma unroll
    for (int i = 0; i < 64; ++i) {
      float hv = __uint_as_float((uint)src[i] << 16);
      ds = fmaf(hv, as[i], ds);
      dd = fmaf(hv, ad[i], dd);
    }
    ds += __shfl_xor(ds, 1, 64);  // pair (2k,2k+1) within same wave
    dd += __shfl_xor(dd, 1, 64);
    if (sh == 0 && ok) {
      s_src[row0 + row] = ds;
      s_dst[row0 + row] = dd;
    }
  }
}

// ---------------- 2-phase multi-block exclusive scan over SCAN_N ints ----------------
__global__ __launch_bounds__(256) void scan1_kernel(const int* __restrict__ src,
                                                    int* __restrict__ dst,
                                                    int* __restrict__ bsum) {
  __shared__ int tsum[256];
  const int b = blockIdx.x;
  const int t = threadIdx.x;
  const int base = b * SCAN_ELEMS + t * 8;
  int v[8];
  int s = 0;
#pragma unroll
  for (int i = 0; i < 8; ++i) {
    int idx = base + i;
    v[i] = (idx < SCAN_N) ? src[idx] : 0;
    s += v[i];
  }
  tsum[t] = s;
  __syncthreads();
  for (int d = 1; d < 256; d <<= 1) {
    int u = (t >= d) ? tsum[t - d] : 0;
    __syncthreads();
    tsum[t] += u;
    __syncthreads();
  }
  int run = (t == 0) ? 0 : tsum[t - 1];
#pragma unroll
  for (int i = 0; i < 8; ++i) {
    int idx = base + i;
    if (idx < SCAN_N) dst[idx] = run;
    run += v[i];
  }
  if (t == 255) bsum[b] = tsum[255];
}

// scan3: each block redundantly scans the 77 block sums in LDS (kills the scan2 launch)
__global__ __launch_bounds__(256) void scan3_kernel(int* __restrict__ dst,
                                                    const int* __restrict__ bsum) {
  __shared__ int s[128];
  const int b = blockIdx.x;
  const int t = threadIdx.x;
  if (t < 128) s[t] = (t < SCAN_BLOCKS) ? bsum[t] : 0;
  __syncthreads();
  for (int d = 1; d < 128; d <<= 1) {
    int u = 0;
    if (t >= d && t < 128) u = s[t - d];
    __syncthreads();
    if (t < 128) s[t] += u;
    __syncthreads();
  }
  const int add = (b == 0) ? 0 : s[b - 1];  // exclusive prefix of block b
  const int base = b * SCAN_ELEMS + t * 8;
#pragma unroll
  for (int i = 0; i < 8; ++i) {
    int idx = base + i;
    if (idx < SCAN_N) dst[idx] += add;
  }
  if (b == 0 && t == 0) dst[SCAN_N] = s[SCAN_BLOCKS - 1];
}

// ---------------- partition into bucket-ordered packed buffer ----------------
// packed word: (row & 127) << 17 | col   (col < 2^17)
__global__ __launch_bounds__(1024) void partition_kernel(const int* __restrict__ erow,
                                                         const int* __restrict__ ecol,
                                                         const int* __restrict__ scanG,
                                                         uint* __restrict__ packed) {
  __shared__ int cur[NB];
  const int b = blockIdx.x;
  const int t = threadIdx.x;
  for (int k = t; k < NB; k += 1024) cur[k] = scanG[k * NBLK + b];
  __syncthreads();
  const int base = b * CHUNK;
  for (int i = base + t * 4; i < base + CHUNK; i += 4096) {
    int4 r4 = *(const int4*)(erow + i);
    int4 c4 = *(const int4*)(ecol + i);
#pragma unroll
    for (int k = 0; k < 4; ++k) {
      int r = (&r4.x)[k];
      int c = (&c4.x)[k];
      int pos = atomicAdd(&cur[r >> 7], 1);
      packed[pos] = ((uint)(r & 127) << 17) | (uint)c;
    }
  }
}

// ---------------- per-bucket scatter into CSR order + row offsets (single global read) ----------------
__global__ __launch_bounds__(512) void bucket_scatter_kernel(const uint* __restrict__ packed,
                                                             const int* __restrict__ scanG,
                                                             int* __restrict__ offs,
                                                             int* __restrict__ scol) {
  __shared__ int cnt[128];
  __shared__ int sc[128];
  const int b = blockIdx.x;
  const int t = threadIdx.x;
  const int beg = scanG[b * NBLK];
  const int end = scanG[(b + 1) * NBLK];
  if (t < 128) cnt[t] = 0;
  __syncthreads();
  // pass 1: load into registers + count (fully unrolled -> stays in VGPRs)
  uint it[SCAT_IT];
  int nit = 0;
#pragma unroll
  for (int k = 0; k < SCAT_IT; ++k) {
    int i = beg + t + k * 512;
    if (i < end) {
      uint p = packed[i];
      it[k] = p;
      nit = k + 1;
      atomicAdd(&cnt[p >> 17], 1);
    }
  }
  __syncthreads();
  if (t < 128) sc[t] = cnt[t];
  __syncthreads();
  for (int d = 1; d < 128; d <<= 1) {
    int v = 0;
    if (t >= d && t < 128) v = sc[t - d];
    __syncthreads();
    if (t < 128) sc[t] += v;
    __syncthreads();
  }
  const int row0 = b << 7;
  if (t < 128) {
    int rstart = beg + sc[t] - cnt[t];  // exclusive
    if (row0 + t < N_NODES) offs[row0 + t] = rstart;
    sc[t] = rstart;  // repurpose as row base
    cnt[t] = 0;      // repurpose as cursor
  }
  if (b == NB - 1 && t == 0) offs[N_NODES] = end;
  __syncthreads();
  // pass 2: scatter from registers
#pragma unroll
  for (int k = 0; k < SCAT_IT; ++k) {
    if (k < nit) {
      uint p = it[k];
      int rl = p >> 17;
      int pos = sc[rl] + atomicAdd(&cnt[rl], 1);
      scol[pos] = (int)(p & 0x1FFFFu);
    }
  }
}

// ---------------- softmax + aggregation (one wave per row) ----------------
// Register softmax -> LDS (att,col) staging -> 16-lane-group uint4 gather (4 edges/iter, x4 unroll)
__global__ __launch_bounds__(256) void attn_kernel(const ushort* __restrict__ h16,
                                                   const float* __restrict__ s_src,
                                                   const float* __restrict__ s_dst,
                                                   const int* __restrict__ offs,
                                                   const int* __restrict__ scol,
                                                   float* __restrict__ out) {
  __shared__ uint2 apair[4][128];  // per-wave (att,col) table
  const int lane = threadIdx.x & 63;
  const int w = threadIdx.x >> 6;
  const int r = blockIdx.x * 4 + w;
  const int o0 = offs[r];
  const int deg = offs[r + 1] - o0;
  const int g = lane >> 4;         // edge group 0..3
  const int fo = (lane & 15) * 8;  // feature offset (8 feats per lane)
  float* orow = out + (size_t)r * OUT_FEAT + fo;

  if (deg == 0) {  // empty segment -> h_prime = 0 -> elu(0) = 0
    if (g == 0) {
      *(float4*)orow = make_float4(0.f, 0.f, 0.f, 0.f);
      *(float4*)(orow + 4) = make_float4(0.f, 0.f, 0.f, 0.f);
    }
    return;
  }

  const float ssrc = s_src[r];
  const ushort* hb = h16 + fo;
  float acc[8] = {0.f, 0.f, 0.f, 0.f, 0.f, 0.f, 0.f, 0.f};

  if (deg <= 128) {
    // ---- register softmax over edge slots lane / lane+64 ----
    int c0 = 0, c1 = 0;
    float p0 = -INFINITY, p1 = -INFINITY;
    if (lane < deg) {
      c0 = scol[o0 + lane];
      float e = ssrc + s_dst[c0];
      p0 = e > 0.f ? e : ALPHA * e;
    }
    if (lane + 64 < deg) {
      c1 = scol[o0 + 64 + lane];
      float e = ssrc + s_dst[c1];
      p1 = e > 0.f ? e : ALPHA * e;
    }
    float m = fmaxf(p0, p1);
#pragma unroll
    for (int off = 32; off >= 1; off >>= 1) m = fmaxf(m, __shfl_xor(m, off, 64));
    p0 = __expf(p0 - m);  // inactive lanes: exp(-inf) = 0
    p1 = __expf(p1 - m);
    float ssum = p0 + p1;
#pragma unroll
    for (int off = 32; off >= 1; off >>= 1) ssum += __shfl_xor(ssum, off, 64);
    const float inv = 1.f / ssum;
    p0 *= inv;  // pre-scaled attention weights (0 for padding slots)
    p1 *= inv;

    // ---- stash (att, col) in LDS; wave-private, no barrier needed ----
    apair[w][lane] = make_uint2(__float_as_uint(p0), (uint)c0);
    apair[w][64 + lane] = make_uint2(__float_as_uint(p1), (uint)c1);

    // ---- gather: group g takes edge j+g, lane covers 8 feats via uint4 ----
    const int degR = (deg + 3) & ~3;  // padded slots have att=0, col=0
#pragma unroll 4
    for (int j = 0; j < degR; j += 4) {
      uint2 pr = apair[w][j + g];
      float att = __uint_as_float(pr.x);
      uint4 v = *(const uint4*)(hb + (size_t)pr.y * OUT_FEAT);
      acc[0] = fmaf(att, bflo(v.x), acc[0]);
      acc[1] = fmaf(att, bfhi(v.x), acc[1]);
      acc[2] = fmaf(att, bflo(v.y), acc[2]);
      acc[3] = fmaf(att, bfhi(v.y), acc[3]);
      acc[4] = fmaf(att, bflo(v.z), acc[4]);
      acc[5] = fmaf(att, bfhi(v.z), acc[5]);
      acc[6] = fmaf(att, bflo(v.w), acc[6]);
      acc[7] = fmaf(att, bfhi(v.w), acc[7]);
    }
  } else {
    // ---- streaming fallback (deg > 128; statistically unreachable) ----
    float m = -INFINITY;
    for (int j = lane; j < deg; j += 64) {
      int c = scol[o0 + j];
      float e = ssrc + s_dst[c];
      e = e > 0.f ? e : ALPHA * e;
      m = fmaxf(m, e);
    }
#pragma unroll
    for (int off = 32; off >= 1; off >>= 1) m = fmaxf(m, __shfl_xor(m, off, 64));
    float ssum = 0.f;
    for (int j = lane; j < deg; j += 64) {
      int c = scol[o0 + j];
      float e = ssrc + s_dst[c];
      e = e > 0.f ? e : ALPHA * e;
      ssum += __expf(e - m);
    }
#pragma unroll
    for (int off = 32; off >= 1; off >>= 1) ssum += __shfl_xor(ssum, off, 64);
    const float inv = 1.f / ssum;
    for (int j = 0; j < deg; j += 4) {
      int jj = j + g;
      float att = 0.f;
      int c = 0;
      if (jj < deg) {
        c = scol[o0 + jj];
        float e = ssrc + s_dst[c];
        e = e > 0.f ? e : ALPHA * e;
        att = __expf(e - m) * inv;
      }
      uint4 v = *(const uint4*)(hb + (size_t)c * OUT_FEAT);
      acc[0] = fmaf(att, bflo(v.x), acc[0]);
      acc[1] = fmaf(att, bfhi(v.x), acc[1]);
      acc[2] = fmaf(att, bflo(v.y), acc[2]);
      acc[3] = fmaf(att, bfhi(v.y), acc[3]);
      acc[4] = fmaf(att, bflo(v.z), acc[4]);
      acc[5] = fmaf(att, bfhi(v.z), acc[5]);
      acc[6] = fmaf(att, bflo(v.w), acc[6]);
      acc[7] = fmaf(att, bfhi(v.w), acc[7]);
    }
  }

  // combine the 4 edge-groups, apply ELU, store (lanes 0-15)
#pragma unroll
  for (int k = 0; k < 8; ++k) {
    acc[k] += __shfl_xor(acc[k], 16, 64);
    acc[k] += __shfl_xor(acc[k], 32, 64);
  }
  if (g == 0) {
#pragma unroll
    for (int k = 0; k < 8; ++k) acc[k] = acc[k] > 0.f ? acc[k] : expm1f(acc[k]);
    *(float4*)orow = make_float4(acc[0], acc[1], acc[2], acc[3]);
    *(float4*)(orow + 4) = make_float4(acc[4], acc[5], acc[6], acc[7]);
  }
}

extern "C" void kernel_launch(void* const* d_in, const int* in_sizes, int n_in,
                              void* d_out, int out_size, void* d_ws, size_t ws_size,
                              hipStream_t stream) {
  const float* x = (const float*)d_in[0];
  const int* erow = (const int*)d_in[1];
  const int* ecol = (const int*)d_in[2];
  const float* W = (const float*)d_in[3];
  const float* a = (const float*)d_in[4];
  float* out = (float*)d_out;

  char* ws = (char*)d_ws;
  size_t off = 0;
  auto alloc = [&](size_t bytes) {
    void* p = ws + off;
    off = (off + bytes + 255) & ~(size_t)255;
    return p;
  };
  const int M_PAD = 782 * GBM;  // 100096 rows
  ushort* h16 = (ushort*)alloc((size_t)M_PAD * OUT_FEAT * sizeof(ushort));  // 25.6 MB
  ushort* Wt = (ushort*)alloc((size_t)IN_FEAT * OUT_FEAT * sizeof(ushort));
  float* s_src = (float*)alloc((size_t)N_NODES * sizeof(float));
  float* s_dst = (float*)alloc((size_t)N_NODES * sizeof(float));
  int* offs = (int*)alloc((size_t)(N_NODES + 1) * sizeof(int));
  int* G = (int*)alloc((size_t)SCAN_N * sizeof(int));            // 625 KB
  int* scanG = (int*)alloc((size_t)(SCAN_N + 1) * sizeof(int));  // 625 KB
  int* bsum = (int*)alloc((size_t)SCAN_BLOCKS * sizeof(int));
  uint* packed = (uint*)alloc((size_t)N_EDGES * sizeof(uint));  // 12.8 MB
  int* scol = (int*)alloc((size_t)N_EDGES * sizeof(int));       // 12.8 MB

  wt_kernel<<<(IN_FEAT * OUT_FEAT) / 256, 256, 0, stream>>>(W, Wt);
  gemm_hist_kernel<<<HIST_BLKS + 782, 256, 0, stream>>>(x, Wt, a, erow, h16, s_src, s_dst, G);
  scan1_kernel<<<SCAN_BLOCKS, 256, 0, stream>>>(G, scanG, bsum);
  scan3_kernel<<<SCAN_BLOCKS, 256, 0, stream>>>(scanG, bsum);
  partition_kernel<<<NBLK, 1024, 0, stream>>>(erow, ecol, scanG, packed);
  bucket_scatter_kernel<<<NB, 512, 0, stream>>>(packed, scanG, offs, scol);
  attn_kernel<<<N_NODES / 4, 256, 0, stream>>>(h16, s_src, s_dst, offs, scol, out);
}

// Round 14
// 213.925 us; speedup vs baseline: 1.2844x; 1.2844x over previous
//
#include <hip/hip_runtime.h>
#include <hip/hip_bf16.h>
#include <math.h>

#define N_NODES 100000
#define N_EDGES 3200000
#define IN_FEAT 256
#define OUT_FEAT 128
#define ALPHA 0.2f
#define NB 782       // ceil(100000/128) buckets of 128 rows
#define NBLK 200     // partition blocks
#define CHUNK 16000  // edges per partition block (200*16000 = 3.2M exact)

#define SCAN_N (NB * NBLK)  // 156400
#define SCAN_ELEMS 2048     // per block (256 thr x 8)
#define SCAN_BLOCKS ((SCAN_N + SCAN_ELEMS - 1) / SCAN_ELEMS)  // 77
#define SCAT_IT 10          // per-thread register staging (512 thr x 10 = 5120)

typedef __attribute__((ext_vector_type(8))) short short8;
typedef __attribute__((ext_vector_type(4))) float f32x4;

__device__ __forceinline__ ushort f2bf(float f) {
  __hip_bfloat16 h = __float2bfloat16(f);
  return __builtin_bit_cast(ushort, h);
}
__device__ __forceinline__ float bflo(uint u) { return __uint_as_float(u << 16); }
__device__ __forceinline__ float bfhi(uint u) { return __uint_as_float(u & 0xFFFF0000u); }

// ---------------- W transpose + bf16 cast: Wt[c][k] = bf16(W[k][c]) ----------------
__global__ __launch_bounds__(256) void wt_kernel(const float* __restrict__ W,
                                                 ushort* __restrict__ Wt) {
  int id = blockIdx.x * 256 + threadIdx.x;
  int c = id >> 8;
  int k = id & 255;
  Wt[id] = f2bf(W[k * OUT_FEAT + c]);
}

// ---------------- fused: hist (blocks 0..199) + gemm h16 (blocks 200..981) ----------------
// Measured-fast staged gemm: A/B tiles in LDS per K-step, 16.9 KB LDS, ~77% occupancy.
#define GBM 128
#define GBK 32
#define A_LD 40
#define C_LD 136
#define HIST_BLKS NBLK

__global__ __launch_bounds__(256) void gemm_hist_kernel(const float* __restrict__ x,
                                                        const ushort* __restrict__ Wt,
                                                        const float* __restrict__ a,
                                                        const int* __restrict__ erow,
                                                        ushort* __restrict__ h16,
                                                        float* __restrict__ s_src,
                                                        float* __restrict__ s_dst,
                                                        int* __restrict__ G) {
  __shared__ union {
    struct { ushort A[GBM * A_LD]; ushort B[OUT_FEAT * A_LD]; } s;
    ushort C[GBM * C_LD];
    int hist[NB];
  } sm;
  __shared__ float sa[2 * OUT_FEAT];
  const int tid = threadIdx.x;

  if (blockIdx.x < HIST_BLKS) {
    // ---------- per-(block,bucket) histogram, LDS atomics only ----------
    const int b = blockIdx.x;
    for (int k = tid; k < NB; k += 256) sm.hist[k] = 0;
    __syncthreads();
    const int base = b * CHUNK;
    for (int i = base + tid; i < base + CHUNK; i += 256) atomicAdd(&sm.hist[erow[i] >> 7], 1);
    __syncthreads();
    for (int k = tid; k < NB; k += 256) G[k * NBLK + b] = sm.hist[k];
    return;
  }

  // ---------- gemm path ----------
  const int row0 = (blockIdx.x - HIST_BLKS) * GBM;
  const int lane = tid & 63;
  const int wave = tid >> 6;
  const int lr = lane & 15;
  const int lg = lane >> 4;

  sa[tid] = a[tid];  // 256 threads == 2*OUT_FEAT; visible after first barrier

  f32x4 acc[2][8];
#pragma unroll
  for (int m = 0; m < 2; ++m)
#pragma unroll
    for (int n = 0; n < 8; ++n) acc[m][n] = (f32x4)(0.f);

  const int sr = tid >> 1;
  const int sh = tid & 1;
  const bool arow_ok = (row0 + sr) < N_NODES;
  const float* xg = x + (size_t)(row0 + sr) * IN_FEAT + sh * 16;
  const ushort* wg = Wt + sr * IN_FEAT + sh * 16;

  for (int ks = 0; ks < IN_FEAT / GBK; ++ks) {
    float4 f[4];
    if (arow_ok) {
#pragma unroll
      for (int i = 0; i < 4; ++i) f[i] = *(const float4*)(xg + ks * GBK + i * 4);
    } else {
#pragma unroll
      for (int i = 0; i < 4; ++i) f[i] = make_float4(0.f, 0.f, 0.f, 0.f);
    }
#pragma unroll
    for (int i = 0; i < 4; ++i) {
      uint2 p;
      p.x = (uint)f2bf(f[i].x) | ((uint)f2bf(f[i].y) << 16);
      p.y = (uint)f2bf(f[i].z) | ((uint)f2bf(f[i].w) << 16);
      *(uint2*)&sm.s.A[sr * A_LD + sh * 16 + i * 4] = p;
    }
    {
      short8 b0 = *(const short8*)(wg + ks * GBK);
      short8 b1 = *(const short8*)(wg + ks * GBK + 8);
      *(short8*)&sm.s.B[sr * A_LD + sh * 16] = b0;
      *(short8*)&sm.s.B[sr * A_LD + sh * 16 + 8] = b1;
    }
    __syncthreads();
    short8 af[2], bf[8];
#pragma unroll
    for (int m = 0; m < 2; ++m)
      af[m] = *(const short8*)&sm.s.A[(wave * 32 + m * 16 + lr) * A_LD + lg * 8];
#pragma unroll
    for (int n = 0; n < 8; ++n)
      bf[n] = *(const short8*)&sm.s.B[(n * 16 + lr) * A_LD + lg * 8];
#pragma unroll
    for (int m = 0; m < 2; ++m)
#pragma unroll
      for (int n = 0; n < 8; ++n)
        acc[m][n] = __builtin_amdgcn_mfma_f32_16x16x32_bf16(af[m], bf[n], acc[m][n], 0, 0, 0);
    __syncthreads();
  }

#pragma unroll
  for (int m = 0; m < 2; ++m)
#pragma unroll
    for (int n = 0; n < 8; ++n)
#pragma unroll
      for (int i = 0; i < 4; ++i)
        sm.C[(wave * 32 + m * 16 + lg * 4 + i) * C_LD + n * 16 + lr] = f2bf(acc[m][n][i]);
  __syncthreads();
  {
    const int row = sr;  // tid>>1
    const bool ok = (row0 + row) < N_NODES;
    const ushort* src = &sm.C[row * C_LD + sh * 64];
    if (ok) {
      ushort* dst = h16 + (size_t)(row0 + row) * OUT_FEAT + sh * 64;
#pragma unroll
      for (int i = 0; i < 8; ++i) *(short8*)(dst + i * 8) = *(const short8*)(src + i * 8);
    }
    // fused s_src/s_dst: dot(h_row, a_src), dot(h_row, a_dst)
    float ds = 0.f, dd = 0.f;
    const float* as = &sa[sh * 64];
    const float* ad = &sa[OUT_FEAT + sh * 64];
#pragma unroll
    for (int i = 0; i < 64; ++i) {
      float hv = __uint_as_float((uint)src[i] << 16);
      ds = fmaf(hv, as[i], ds);
      dd = fmaf(hv, ad[i], dd);
    }
    ds += __shfl_xor(ds, 1, 64);  // pair (2k,2k+1) within same wave
    dd += __shfl_xor(dd, 1, 64);
    if (sh == 0 && ok) {
      s_src[row0 + row] = ds;
      s_dst[row0 + row] = dd;
    }
  }
}

// ---------------- 2-phase multi-block exclusive scan over SCAN_N ints ----------------
__global__ __launch_bounds__(256) void scan1_kernel(const int* __restrict__ src,
                                                    int* __restrict__ dst,
                                                    int* __restrict__ bsum) {
  __shared__ int tsum[256];
  const int b = blockIdx.x;
  const int t = threadIdx.x;
  const int base = b * SCAN_ELEMS + t * 8;
  int v[8];
  int s = 0;
#pragma unroll
  for (int i = 0; i < 8; ++i) {
    int idx = base + i;
    v[i] = (idx < SCAN_N) ? src[idx] : 0;
    s += v[i];
  }
  tsum[t] = s;
  __syncthreads();
  for (int d = 1; d < 256; d <<= 1) {
    int u = (t >= d) ? tsum[t - d] : 0;
    __syncthreads();
    tsum[t] += u;
    __syncthreads();
  }
  int run = (t == 0) ? 0 : tsum[t - 1];
#pragma unroll
  for (int i = 0; i < 8; ++i) {
    int idx = base + i;
    if (idx < SCAN_N) dst[idx] = run;
    run += v[i];
  }
  if (t == 255) bsum[b] = tsum[255];
}

// scan3: each block redundantly scans the 77 block sums in LDS (kills the scan2 launch)
__global__ __launch_bounds__(256) void scan3_kernel(int* __restrict__ dst,
                                                    const int* __restrict__ bsum) {
  __shared__ int s[128];
  const int b = blockIdx.x;
  const int t = threadIdx.x;
  if (t < 128) s[t] = (t < SCAN_BLOCKS) ? bsum[t] : 0;
  __syncthreads();
  for (int d = 1; d < 128; d <<= 1) {
    int u = 0;
    if (t >= d && t < 128) u = s[t - d];
    __syncthreads();
    if (t < 128) s[t] += u;
    __syncthreads();
  }
  const int add = (b == 0) ? 0 : s[b - 1];  // exclusive prefix of block b
  const int base = b * SCAN_ELEMS + t * 8;
#pragma unroll
  for (int i = 0; i < 8; ++i) {
    int idx = base + i;
    if (idx < SCAN_N) dst[idx] += add;
  }
  if (b == 0 && t == 0) dst[SCAN_N] = s[SCAN_BLOCKS - 1];
}

// ---------------- partition into bucket-ordered packed buffer ----------------
// packed word: (row & 127) << 17 | col   (col < 2^17)
__global__ __launch_bounds__(1024) void partition_kernel(const int* __restrict__ erow,
                                                         const int* __restrict__ ecol,
                                                         const int* __restrict__ scanG,
                                                         uint* __restrict__ packed) {
  __shared__ int cur[NB];
  const int b = blockIdx.x;
  const int t = threadIdx.x;
  for (int k = t; k < NB; k += 1024) cur[k] = scanG[k * NBLK + b];
  __syncthreads();
  const int base = b * CHUNK;
  for (int i = base + t * 4; i < base + CHUNK; i += 4096) {
    int4 r4 = *(const int4*)(erow + i);
    int4 c4 = *(const int4*)(ecol + i);
#pragma unroll
    for (int k = 0; k < 4; ++k) {
      int r = (&r4.x)[k];
      int c = (&c4.x)[k];
      int pos = atomicAdd(&cur[r >> 7], 1);
      packed[pos] = ((uint)(r & 127) << 17) | (uint)c;
    }
  }
}

// ---------------- per-bucket scatter into CSR order + row offsets (single global read) ----------------
__global__ __launch_bounds__(512) void bucket_scatter_kernel(const uint* __restrict__ packed,
                                                             const int* __restrict__ scanG,
                                                             int* __restrict__ offs,
                                                             int* __restrict__ scol) {
  __shared__ int cnt[128];
  __shared__ int sc[128];
  const int b = blockIdx.x;
  const int t = threadIdx.x;
  const int beg = scanG[b * NBLK];
  const int end = scanG[(b + 1) * NBLK];
  if (t < 128) cnt[t] = 0;
  __syncthreads();
  // pass 1: load into registers + count (fully unrolled -> stays in VGPRs)
  uint it[SCAT_IT];
  int nit = 0;
#pragma unroll
  for (int k = 0; k < SCAT_IT; ++k) {
    int i = beg + t + k * 512;
    if (i < end) {
      uint p = packed[i];
      it[k] = p;
      nit = k + 1;
      atomicAdd(&cnt[p >> 17], 1);
    }
  }
  __syncthreads();
  if (t < 128) sc[t] = cnt[t];
  __syncthreads();
  for (int d = 1; d < 128; d <<= 1) {
    int v = 0;
    if (t >= d && t < 128) v = sc[t - d];
    __syncthreads();
    if (t < 128) sc[t] += v;
    __syncthreads();
  }
  const int row0 = b << 7;
  if (t < 128) {
    int rstart = beg + sc[t] - cnt[t];  // exclusive
    if (row0 + t < N_NODES) offs[row0 + t] = rstart;
    sc[t] = rstart;  // repurpose as row base
    cnt[t] = 0;      // repurpose as cursor
  }
  if (b == NB - 1 && t == 0) offs[N_NODES] = end;
  __syncthreads();
  // pass 2: scatter from registers
#pragma unroll
  for (int k = 0; k < SCAT_IT; ++k) {
    if (k < nit) {
      uint p = it[k];
      int rl = p >> 17;
      int pos = sc[rl] + atomicAdd(&cnt[rl], 1);
      scol[pos] = (int)(p & 0x1FFFFu);
    }
  }
}

// ---------------- softmax + aggregation (one wave per row) ----------------
// Register softmax -> LDS (att,col) staging -> 16-lane-group uint4 gather (4 edges/iter, x4 unroll)
__global__ __launch_bounds__(256) void attn_kernel(const ushort* __restrict__ h16,
                                                   const float* __restrict__ s_src,
                                                   const float* __restrict__ s_dst,
                                                   const int* __restrict__ offs,
                                                   const int* __restrict__ scol,
                                                   float* __restrict__ out) {
  __shared__ uint2 apair[4][128];  // per-wave (att,col) table
  const int lane = threadIdx.x & 63;
  const int w = threadIdx.x >> 6;
  const int r = blockIdx.x * 4 + w;
  const int o0 = offs[r];
  const int deg = offs[r + 1] - o0;
  const int g = lane >> 4;         // edge group 0..3
  const int fo = (lane & 15) * 8;  // feature offset (8 feats per lane)
  float* orow = out + (size_t)r * OUT_FEAT + fo;

  if (deg == 0) {  // empty segment -> h_prime = 0 -> elu(0) = 0
    if (g == 0) {
      *(float4*)orow = make_float4(0.f, 0.f, 0.f, 0.f);
      *(float4*)(orow + 4) = make_float4(0.f, 0.f, 0.f, 0.f);
    }
    return;
  }

  const float ssrc = s_src[r];
  const ushort* hb = h16 + fo;
  float acc[8] = {0.f, 0.f, 0.f, 0.f, 0.f, 0.f, 0.f, 0.f};

  if (deg <= 128) {
    // ---- register softmax over edge slots lane / lane+64 ----
    int c0 = 0, c1 = 0;
    float p0 = -INFINITY, p1 = -INFINITY;
    if (lane < deg) {
      c0 = scol[o0 + lane];
      float e = ssrc + s_dst[c0];
      p0 = e > 0.f ? e : ALPHA * e;
    }
    if (lane + 64 < deg) {
      c1 = scol[o0 + 64 + lane];
      float e = ssrc + s_dst[c1];
      p1 = e > 0.f ? e : ALPHA * e;
    }
    float m = fmaxf(p0, p1);
#pragma unroll
    for (int off = 32; off >= 1; off >>= 1) m = fmaxf(m, __shfl_xor(m, off, 64));
    p0 = __expf(p0 - m);  // inactive lanes: exp(-inf) = 0
    p1 = __expf(p1 - m);
    float ssum = p0 + p1;
#pragma unroll
    for (int off = 32; off >= 1; off >>= 1) ssum += __shfl_xor(ssum, off, 64);
    const float inv = 1.f / ssum;
    p0 *= inv;  // pre-scaled attention weights (0 for padding slots)
    p1 *= inv;

    // ---- stash (att, col) in LDS; wave-private, no barrier needed ----
    apair[w][lane] = make_uint2(__float_as_uint(p0), (uint)c0);
    apair[w][64 + lane] = make_uint2(__float_as_uint(p1), (uint)c1);

    // ---- gather: group g takes edge j+g, lane covers 8 feats via uint4 ----
    const int degR = (deg + 3) & ~3;  // padded slots have att=0, col=0
#pragma unroll 4
    for (int j = 0; j < degR; j += 4) {
      uint2 pr = apair[w][j + g];
      float att = __uint_as_float(pr.x);
      uint4 v = *(const uint4*)(hb + (size_t)pr.y * OUT_FEAT);
      acc[0] = fmaf(att, bflo(v.x), acc[0]);
      acc[1] = fmaf(att, bfhi(v.x), acc[1]);
      acc[2] = fmaf(att, bflo(v.y), acc[2]);
      acc[3] = fmaf(att, bfhi(v.y), acc[3]);
      acc[4] = fmaf(att, bflo(v.z), acc[4]);
      acc[5] = fmaf(att, bfhi(v.z), acc[5]);
      acc[6] = fmaf(att, bflo(v.w), acc[6]);
      acc[7] = fmaf(att, bfhi(v.w), acc[7]);
    }
  } else {
    // ---- streaming fallback (deg > 128; statistically unreachable) ----
    float m = -INFINITY;
    for (int j = lane; j < deg; j += 64) {
      int c = scol[o0 + j];
      float e = ssrc + s_dst[c];
      e = e > 0.f ? e : ALPHA * e;
      m = fmaxf(m, e);
    }
#pragma unroll
    for (int off = 32; off >= 1; off >>= 1) m = fmaxf(m, __shfl_xor(m, off, 64));
    float ssum = 0.f;
    for (int j = lane; j < deg; j += 64) {
      int c = scol[o0 + j];
      float e = ssrc + s_dst[c];
      e = e > 0.f ? e : ALPHA * e;
      ssum += __expf(e - m);
    }
#pragma unroll
    for (int off = 32; off >= 1; off >>= 1) ssum += __shfl_xor(ssum, off, 64);
    const float inv = 1.f / ssum;
    for (int j = 0; j < deg; j += 4) {
      int jj = j + g;
      float att = 0.f;
      int c = 0;
      if (jj < deg) {
        c = scol[o0 + jj];
        float e = ssrc + s_dst[c];
        e = e > 0.f ? e : ALPHA * e;
        att = __expf(e - m) * inv;
      }
      uint4 v = *(const uint4*)(hb + (size_t)c * OUT_FEAT);
      acc[0] = fmaf(att, bflo(v.x), acc[0]);
      acc[1] = fmaf(att, bfhi(v.x), acc[1]);
      acc[2] = fmaf(att, bflo(v.y), acc[2]);
      acc[3] = fmaf(att, bfhi(v.y), acc[3]);
      acc[4] = fmaf(att, bflo(v.z), acc[4]);
      acc[5] = fmaf(att, bfhi(v.z), acc[5]);
      acc[6] = fmaf(att, bflo(v.w), acc[6]);
      acc[7] = fmaf(att, bfhi(v.w), acc[7]);
    }
  }

  // combine the 4 edge-groups, apply ELU, store (lanes 0-15)
#pragma unroll
  for (int k = 0; k < 8; ++k) {
    acc[k] += __shfl_xor(acc[k], 16, 64);
    acc[k] += __shfl_xor(acc[k], 32, 64);
  }
  if (g == 0) {
#pragma unroll
    for (int k = 0; k < 8; ++k) acc[k] = acc[k] > 0.f ? acc[k] : expm1f(acc[k]);
    *(float4*)orow = make_float4(acc[0], acc[1], acc[2], acc[3]);
    *(float4*)(orow + 4) = make_float4(acc[4], acc[5], acc[6], acc[7]);
  }
}

extern "C" void kernel_launch(void* const* d_in, const int* in_sizes, int n_in,
                              void* d_out, int out_size, void* d_ws, size_t ws_size,
                              hipStream_t stream) {
  const float* x = (const float*)d_in[0];
  const int* erow = (const int*)d_in[1];
  const int* ecol = (const int*)d_in[2];
  const float* W = (const float*)d_in[3];
  const float* a = (const float*)d_in[4];
  float* out = (float*)d_out;

  char* ws = (char*)d_ws;
  size_t off = 0;
  auto alloc = [&](size_t bytes) {
    void* p = ws + off;
    off = (off + bytes + 255) & ~(size_t)255;
    return p;
  };
  const int M_PAD = 782 * GBM;  // 100096 rows
  ushort* h16 = (ushort*)alloc((size_t)M_PAD * OUT_FEAT * sizeof(ushort));  // 25.6 MB
  ushort* Wt = (ushort*)alloc((size_t)IN_FEAT * OUT_FEAT * sizeof(ushort));
  float* s_src = (float*)alloc((size_t)N_NODES * sizeof(float));
  float* s_dst = (float*)alloc((size_t)N_NODES * sizeof(float));
  int* offs = (int*)alloc((size_t)(N_NODES + 1) * sizeof(int));
  int* G = (int*)alloc((size_t)SCAN_N * sizeof(int));            // 625 KB
  int* scanG = (int*)alloc((size_t)(SCAN_N + 1) * sizeof(int));  // 625 KB
  int* bsum = (int*)alloc((size_t)SCAN_BLOCKS * sizeof(int));
  uint* packed = (uint*)alloc((size_t)N_EDGES * sizeof(uint));  // 12.8 MB
  int* scol = (int*)alloc((size_t)N_EDGES * sizeof(int));       // 12.8 MB

  wt_kernel<<<(IN_FEAT * OUT_FEAT) / 256, 256, 0, stream>>>(W, Wt);
  gemm_hist_kernel<<<HIST_BLKS + 782, 256, 0, stream>>>(x, Wt, a, erow, h16, s_src, s_dst, G);
  scan1_kernel<<<SCAN_BLOCKS, 256, 0, stream>>>(G, scanG, bsum);
  scan3_kernel<<<SCAN_BLOCKS, 256, 0, stream>>>(scanG, bsum);
  partition_kernel<<<NBLK, 1024, 0, stream>>>(erow, ecol, scanG, packed);
  bucket_scatter_kernel<<<NB, 512, 0, stream>>>(packed, scanG, offs, scol);
  attn_kernel<<<N_NODES / 4, 256, 0, stream>>>(h16, s_src, s_dst, offs, scol, out);
}

// Round 16
// 212.354 us; speedup vs baseline: 1.2939x; 1.0074x over previous
//
#include <hip/hip_runtime.h>
#include <hip/hip_bf16.h>
#include <math.h>

#define N_NODES 100000
#define N_EDGES 3200000
#define IN_FEAT 256
#define OUT_FEAT 128
#define ALPHA 0.2f
#define NB 782       // ceil(100000/128) buckets of 128 rows
#define NBLK 200     // partition blocks
#define CHUNK 16000  // edges per partition block (200*16000 = 3.2M exact)

#define SCAN_N (NB * NBLK)  // 156400
#define SCAN_ELEMS 2048     // per block (256 thr x 8)
#define SCAN_BLOCKS ((SCAN_N + SCAN_ELEMS - 1) / SCAN_ELEMS)  // 77
#define SCAT_IT 10          // per-thread register staging (512 thr x 10 = 5120)

typedef __attribute__((ext_vector_type(8))) short short8;
typedef __attribute__((ext_vector_type(4))) float f32x4;

__device__ __forceinline__ ushort f2bf(float f) {
  __hip_bfloat16 h = __float2bfloat16(f);
  return __builtin_bit_cast(ushort, h);
}
__device__ __forceinline__ float bflo(uint u) { return __uint_as_float(u << 16); }
__device__ __forceinline__ float bfhi(uint u) { return __uint_as_float(u & 0xFFFF0000u); }

// ---------------- W transpose + bf16 cast: Wt[c][k] = bf16(W[k][c]) ----------------
__global__ __launch_bounds__(256) void wt_kernel(const float* __restrict__ W,
                                                 ushort* __restrict__ Wt) {
  int id = blockIdx.x * 256 + threadIdx.x;
  int c = id >> 8;
  int k = id & 255;
  Wt[id] = f2bf(W[k * OUT_FEAT + c]);
}

// ---------------- fused: hist (blocks 0..199) + gemm h16 (blocks 200..981) ----------------
// Measured-fast staged gemm: A/B tiles in LDS per K-step, 16.9 KB LDS, ~77% occupancy.
#define GBM 128
#define GBK 32
#define A_LD 40
#define C_LD 136
#define HIST_BLKS NBLK

__global__ __launch_bounds__(256) void gemm_hist_kernel(const float* __restrict__ x,
                                                        const ushort* __restrict__ Wt,
                                                        const float* __restrict__ a,
                                                        const int* __restrict__ erow,
                                                        ushort* __restrict__ h16,
                                                        float* __restrict__ s_src,
                                                        float* __restrict__ s_dst,
                                                        int* __restrict__ G) {
  __shared__ union {
    struct { ushort A[GBM * A_LD]; ushort B[OUT_FEAT * A_LD]; } s;
    ushort C[GBM * C_LD];
    int hist[NB];
  } sm;
  __shared__ float sa[2 * OUT_FEAT];
  const int tid = threadIdx.x;

  if (blockIdx.x < HIST_BLKS) {
    // ---------- per-(block,bucket) histogram, LDS atomics only ----------
    const int b = blockIdx.x;
    for (int k = tid; k < NB; k += 256) sm.hist[k] = 0;
    __syncthreads();
    const int base = b * CHUNK;
    for (int i = base + tid; i < base + CHUNK; i += 256) atomicAdd(&sm.hist[erow[i] >> 7], 1);
    __syncthreads();
    for (int k = tid; k < NB; k += 256) G[k * NBLK + b] = sm.hist[k];
    return;
  }

  // ---------- gemm path ----------
  const int row0 = (blockIdx.x - HIST_BLKS) * GBM;
  const int lane = tid & 63;
  const int wave = tid >> 6;
  const int lr = lane & 15;
  const int lg = lane >> 4;

  sa[tid] = a[tid];  // 256 threads == 2*OUT_FEAT; visible after first barrier

  f32x4 acc[2][8];
#pragma unroll
  for (int m = 0; m < 2; ++m)
#pragma unroll
    for (int n = 0; n < 8; ++n) acc[m][n] = (f32x4)(0.f);

  const int sr = tid >> 1;
  const int sh = tid & 1;
  const bool arow_ok = (row0 + sr) < N_NODES;
  const float* xg = x + (size_t)(row0 + sr) * IN_FEAT + sh * 16;
  const ushort* wg = Wt + sr * IN_FEAT + sh * 16;

  for (int ks = 0; ks < IN_FEAT / GBK; ++ks) {
    float4 f[4];
    if (arow_ok) {
#pragma unroll
      for (int i = 0; i < 4; ++i) f[i] = *(const float4*)(xg + ks * GBK + i * 4);
    } else {
#pragma unroll
      for (int i = 0; i < 4; ++i) f[i] = make_float4(0.f, 0.f, 0.f, 0.f);
    }
#pragma unroll
    for (int i = 0; i < 4; ++i) {
      uint2 p;
      p.x = (uint)f2bf(f[i].x) | ((uint)f2bf(f[i].y) << 16);
      p.y = (uint)f2bf(f[i].z) | ((uint)f2bf(f[i].w) << 16);
      *(uint2*)&sm.s.A[sr * A_LD + sh * 16 + i * 4] = p;
    }
    {
      short8 b0 = *(const short8*)(wg + ks * GBK);
      short8 b1 = *(const short8*)(wg + ks * GBK + 8);
      *(short8*)&sm.s.B[sr * A_LD + sh * 16] = b0;
      *(short8*)&sm.s.B[sr * A_LD + sh * 16 + 8] = b1;
    }
    __syncthreads();
    short8 af[2], bf[8];
#pragma unroll
    for (int m = 0; m < 2; ++m)
      af[m] = *(const short8*)&sm.s.A[(wave * 32 + m * 16 + lr) * A_LD + lg * 8];
#pragma unroll
    for (int n = 0; n < 8; ++n)
      bf[n] = *(const short8*)&sm.s.B[(n * 16 + lr) * A_LD + lg * 8];
#pragma unroll
    for (int m = 0; m < 2; ++m)
#pragma unroll
      for (int n = 0; n < 8; ++n)
        acc[m][n] = __builtin_amdgcn_mfma_f32_16x16x32_bf16(af[m], bf[n], acc[m][n], 0, 0, 0);
    __syncthreads();
  }

#pragma unroll
  for (int m = 0; m < 2; ++m)
#pragma unroll
    for (int n = 0; n < 8; ++n)
#pragma unroll
      for (int i = 0; i < 4; ++i)
        sm.C[(wave * 32 + m * 16 + lg * 4 + i) * C_LD + n * 16 + lr] = f2bf(acc[m][n][i]);
  __syncthreads();
  {
    const int row = sr;  // tid>>1
    const bool ok = (row0 + row) < N_NODES;
    const ushort* src = &sm.C[row * C_LD + sh * 64];
    if (ok) {
      ushort* dst = h16 + (size_t)(row0 + row) * OUT_FEAT + sh * 64;
#pragma unroll
      for (int i = 0; i < 8; ++i) *(short8*)(dst + i * 8) = *(const short8*)(src + i * 8);
    }
    // fused s_src/s_dst: dot(h_row, a_src), dot(h_row, a_dst)
    float ds = 0.f, dd = 0.f;
    const float* as = &sa[sh * 64];
    const float* ad = &sa[OUT_FEAT + sh * 64];
#pragma unroll
    for (int i = 0; i < 64; ++i) {
      float hv = __uint_as_float((uint)src[i] << 16);
      ds = fmaf(hv, as[i], ds);
      dd = fmaf(hv, ad[i], dd);
    }
    ds += __shfl_xor(ds, 1, 64);  // pair (2k,2k+1) within same wave
    dd += __shfl_xor(dd, 1, 64);
    if (sh == 0 && ok) {
      s_src[row0 + row] = ds;
      s_dst[row0 + row] = dd;
    }
  }
}

// ---------------- 2-phase multi-block exclusive scan over SCAN_N ints ----------------
__global__ __launch_bounds__(256) void scan1_kernel(const int* __restrict__ src,
                                                    int* __restrict__ dst,
                                                    int* __restrict__ bsum) {
  __shared__ int tsum[256];
  const int b = blockIdx.x;
  const int t = threadIdx.x;
  const int base = b * SCAN_ELEMS + t * 8;
  int v[8];
  int s = 0;
#pragma unroll
  for (int i = 0; i < 8; ++i) {
    int idx = base + i;
    v[i] = (idx < SCAN_N) ? src[idx] : 0;
    s += v[i];
  }
  tsum[t] = s;
  __syncthreads();
  for (int d = 1; d < 256; d <<= 1) {
    int u = (t >= d) ? tsum[t - d] : 0;
    __syncthreads();
    tsum[t] += u;
    __syncthreads();
  }
  int run = (t == 0) ? 0 : tsum[t - 1];
#pragma unroll
  for (int i = 0; i < 8; ++i) {
    int idx = base + i;
    if (idx < SCAN_N) dst[idx] = run;
    run += v[i];
  }
  if (t == 255) bsum[b] = tsum[255];
}

// scan3: each block redundantly scans the 77 block sums in LDS (kills the scan2 launch)
__global__ __launch_bounds__(256) void scan3_kernel(int* __restrict__ dst,
                                                    const int* __restrict__ bsum) {
  __shared__ int s[128];
  const int b = blockIdx.x;
  const int t = threadIdx.x;
  if (t < 128) s[t] = (t < SCAN_BLOCKS) ? bsum[t] : 0;
  __syncthreads();
  for (int d = 1; d < 128; d <<= 1) {
    int u = 0;
    if (t >= d && t < 128) u = s[t - d];
    __syncthreads();
    if (t < 128) s[t] += u;
    __syncthreads();
  }
  const int add = (b == 0) ? 0 : s[b - 1];  // exclusive prefix of block b
  const int base = b * SCAN_ELEMS + t * 8;
#pragma unroll
  for (int i = 0; i < 8; ++i) {
    int idx = base + i;
    if (idx < SCAN_N) dst[idx] += add;
  }
  if (b == 0 && t == 0) dst[SCAN_N] = s[SCAN_BLOCKS - 1];
}

// ---------------- partition into bucket-ordered packed buffer ----------------
// packed word: (row & 127) << 17 | col   (col < 2^17)
__global__ __launch_bounds__(1024) void partition_kernel(const int* __restrict__ erow,
                                                         const int* __restrict__ ecol,
                                                         const int* __restrict__ scanG,
                                                         uint* __restrict__ packed) {
  __shared__ int cur[NB];
  const int b = blockIdx.x;
  const int t = threadIdx.x;
  for (int k = t; k < NB; k += 1024) cur[k] = scanG[k * NBLK + b];
  __syncthreads();
  const int base = b * CHUNK;
  for (int i = base + t * 4; i < base + CHUNK; i += 4096) {
    int4 r4 = *(const int4*)(erow + i);
    int4 c4 = *(const int4*)(ecol + i);
#pragma unroll
    for (int k = 0; k < 4; ++k) {
      int r = (&r4.x)[k];
      int c = (&c4.x)[k];
      int pos = atomicAdd(&cur[r >> 7], 1);
      packed[pos] = ((uint)(r & 127) << 17) | (uint)c;
    }
  }
}

// ---------------- per-bucket scatter into CSR order + row offsets (single global read) ----------------
__global__ __launch_bounds__(512) void bucket_scatter_kernel(const uint* __restrict__ packed,
                                                             const int* __restrict__ scanG,
                                                             int* __restrict__ offs,
                                                             int* __restrict__ scol) {
  __shared__ int cnt[128];
  __shared__ int sc[128];
  const int b = blockIdx.x;
  const int t = threadIdx.x;
  const int beg = scanG[b * NBLK];
  const int end = scanG[(b + 1) * NBLK];
  if (t < 128) cnt[t] = 0;
  __syncthreads();
  // pass 1: load into registers + count (fully unrolled -> stays in VGPRs)
  uint it[SCAT_IT];
  int nit = 0;
#pragma unroll
  for (int k = 0; k < SCAT_IT; ++k) {
    int i = beg + t + k * 512;
    if (i < end) {
      uint p = packed[i];
      it[k] = p;
      nit = k + 1;
      atomicAdd(&cnt[p >> 17], 1);
    }
  }
  __syncthreads();
  if (t < 128) sc[t] = cnt[t];
  __syncthreads();
  for (int d = 1; d < 128; d <<= 1) {
    int v = 0;
    if (t >= d && t < 128) v = sc[t - d];
    __syncthreads();
    if (t < 128) sc[t] += v;
    __syncthreads();
  }
  const int row0 = b << 7;
  if (t < 128) {
    int rstart = beg + sc[t] - cnt[t];  // exclusive
    if (row0 + t < N_NODES) offs[row0 + t] = rstart;
    sc[t] = rstart;  // repurpose as row base
    cnt[t] = 0;      // repurpose as cursor
  }
  if (b == NB - 1 && t == 0) offs[N_NODES] = end;
  __syncthreads();
  // pass 2: scatter from registers
#pragma unroll
  for (int k = 0; k < SCAT_IT; ++k) {
    if (k < nit) {
      uint p = it[k];
      int rl = p >> 17;
      int pos = sc[rl] + atomicAdd(&cnt[rl], 1);
      scol[pos] = (int)(p & 0x1FFFFu);
    }
  }
}

// ---------------- softmax + aggregation (one wave per row) ----------------
// Register softmax -> LDS (att,col) staging -> 16-lane-group uint4 gather (4 edges/iter, x4 unroll)
__global__ __launch_bounds__(256) void attn_kernel(const ushort* __restrict__ h16,
                                                   const float* __restrict__ s_src,
                                                   const float* __restrict__ s_dst,
                                                   const int* __restrict__ offs,
                                                   const int* __restrict__ scol,
                                                   float* __restrict__ out) {
  __shared__ uint2 apair[4][128];  // per-wave (att,col) table
  const int lane = threadIdx.x & 63;
  const int w = threadIdx.x >> 6;
  const int r = blockIdx.x * 4 + w;
  const int o0 = offs[r];
  const int deg = offs[r + 1] - o0;
  const int g = lane >> 4;         // edge group 0..3
  const int fo = (lane & 15) * 8;  // feature offset (8 feats per lane)
  float* orow = out + (size_t)r * OUT_FEAT + fo;

  if (deg == 0) {  // empty segment -> h_prime = 0 -> elu(0) = 0
    if (g == 0) {
      *(float4*)orow = make_float4(0.f, 0.f, 0.f, 0.f);
      *(float4*)(orow + 4) = make_float4(0.f, 0.f, 0.f, 0.f);
    }
    return;
  }

  const float ssrc = s_src[r];
  const ushort* hb = h16 + fo;
  float acc[8] = {0.f, 0.f, 0.f, 0.f, 0.f, 0.f, 0.f, 0.f};

  if (deg <= 128) {
    // ---- register softmax over edge slots lane / lane+64 ----
    int c0 = 0, c1 = 0;
    float p0 = -INFINITY, p1 = -INFINITY;
    if (lane < deg) {
      c0 = scol[o0 + lane];
      float e = ssrc + s_dst[c0];
      p0 = e > 0.f ? e : ALPHA * e;
    }
    if (lane + 64 < deg) {
      c1 = scol[o0 + 64 + lane];
      float e = ssrc + s_dst[c1];
      p1 = e > 0.f ? e : ALPHA * e;
    }
    float m = fmaxf(p0, p1);
#pragma unroll
    for (int off = 32; off >= 1; off >>= 1) m = fmaxf(m, __shfl_xor(m, off, 64));
    p0 = __expf(p0 - m);  // inactive lanes: exp(-inf) = 0
    p1 = __expf(p1 - m);
    float ssum = p0 + p1;
#pragma unroll
    for (int off = 32; off >= 1; off >>= 1) ssum += __shfl_xor(ssum, off, 64);
    const float inv = 1.f / ssum;
    p0 *= inv;  // pre-scaled attention weights (0 for padding slots)
    p1 *= inv;

    // ---- stash (att, col) in LDS; wave-private, no barrier needed ----
    apair[w][lane] = make_uint2(__float_as_uint(p0), (uint)c0);
    apair[w][64 + lane] = make_uint2(__float_as_uint(p1), (uint)c1);

    // ---- gather: group g takes edge j+g, lane covers 8 feats via uint4 ----
    const int degR = (deg + 3) & ~3;  // padded slots have att=0, col=0
#pragma unroll 4
    for (int j = 0; j < degR; j += 4) {
      uint2 pr = apair[w][j + g];
      float att = __uint_as_float(pr.x);
      uint4 v = *(const uint4*)(hb + (size_t)pr.y * OUT_FEAT);
      acc[0] = fmaf(att, bflo(v.x), acc[0]);
      acc[1] = fmaf(att, bfhi(v.x), acc[1]);
      acc[2] = fmaf(att, bflo(v.y), acc[2]);
      acc[3] = fmaf(att, bfhi(v.y), acc[3]);
      acc[4] = fmaf(att, bflo(v.z), acc[4]);
      acc[5] = fmaf(att, bfhi(v.z), acc[5]);
      acc[6] = fmaf(att, bflo(v.w), acc[6]);
      acc[7] = fmaf(att, bfhi(v.w), acc[7]);
    }
  } else {
    // ---- streaming fallback (deg > 128; statistically unreachable) ----
    float m = -INFINITY;
    for (int j = lane; j < deg; j += 64) {
      int c = scol[o0 + j];
      float e = ssrc + s_dst[c];
      e = e > 0.f ? e : ALPHA * e;
      m = fmaxf(m, e);
    }
#pragma unroll
    for (int off = 32; off >= 1; off >>= 1) m = fmaxf(m, __shfl_xor(m, off, 64));
    float ssum = 0.f;
    for (int j = lane; j < deg; j += 64) {
      int c = scol[o0 + j];
      float e = ssrc + s_dst[c];
      e = e > 0.f ? e : ALPHA * e;
      ssum += __expf(e - m);
    }
#pragma unroll
    for (int off = 32; off >= 1; off >>= 1) ssum += __shfl_xor(ssum, off, 64);
    const float inv = 1.f / ssum;
    for (int j = 0; j < deg; j += 4) {
      int jj = j + g;
      float att = 0.f;
      int c = 0;
      if (jj < deg) {
        c = scol[o0 + jj];
        float e = ssrc + s_dst[c];
        e = e > 0.f ? e : ALPHA * e;
        att = __expf(e - m) * inv;
      }
      uint4 v = *(const uint4*)(hb + (size_t)c * OUT_FEAT);
      acc[0] = fmaf(att, bflo(v.x), acc[0]);
      acc[1] = fmaf(att, bfhi(v.x), acc[1]);
      acc[2] = fmaf(att, bflo(v.y), acc[2]);
      acc[3] = fmaf(att, bfhi(v.y), acc[3]);
      acc[4] = fmaf(att, bflo(v.z), acc[4]);
      acc[5] = fmaf(att, bfhi(v.z), acc[5]);
      acc[6] = fmaf(att, bflo(v.w), acc[6]);
      acc[7] = fmaf(att, bfhi(v.w), acc[7]);
    }
  }

  // combine the 4 edge-groups, apply ELU, store (lanes 0-15)
#pragma unroll
  for (int k = 0; k < 8; ++k) {
    acc[k] += __shfl_xor(acc[k], 16, 64);
    acc[k] += __shfl_xor(acc[k], 32, 64);
  }
  if (g == 0) {
#pragma unroll
    for (int k = 0; k < 8; ++k) acc[k] = acc[k] > 0.f ? acc[k] : expm1f(acc[k]);
    *(float4*)orow = make_float4(acc[0], acc[1], acc[2], acc[3]);
    *(float4*)(orow + 4) = make_float4(acc[4], acc[5], acc[6], acc[7]);
  }
}

extern "C" void kernel_launch(void* const* d_in, const int* in_sizes, int n_in,
                              void* d_out, int out_size, void* d_ws, size_t ws_size,
                              hipStream_t stream) {
  const float* x = (const float*)d_in[0];
  const int* erow = (const int*)d_in[1];
  const int* ecol = (const int*)d_in[2];
  const float* W = (const float*)d_in[3];
  const float* a = (const float*)d_in[4];
  float* out = (float*)d_out;

  char* ws = (char*)d_ws;
  size_t off = 0;
  auto alloc = [&](size_t bytes) {
    void* p = ws + off;
    off = (off + bytes + 255) & ~(size_t)255;
    return p;
  };
  const int M_PAD = 782 * GBM;  // 100096 rows
  ushort* h16 = (ushort*)alloc((size_t)M_PAD * OUT_FEAT * sizeof(ushort));  // 25.6 MB
  ushort* Wt = (ushort*)alloc((size_t)IN_FEAT * OUT_FEAT * sizeof(ushort));
  float* s_src = (float*)alloc((size_t)N_NODES * sizeof(float));
  float* s_dst = (float*)alloc((size_t)N_NODES * sizeof(float));
  int* offs = (int*)alloc((size_t)(N_NODES + 1) * sizeof(int));
  int* G = (int*)alloc((size_t)SCAN_N * sizeof(int));            // 625 KB
  int* scanG = (int*)alloc((size_t)(SCAN_N + 1) * sizeof(int));  // 625 KB
  int* bsum = (int*)alloc((size_t)SCAN_BLOCKS * sizeof(int));
  uint* packed = (uint*)alloc((size_t)N_EDGES * sizeof(uint));  // 12.8 MB
  int* scol = (int*)alloc((size_t)N_EDGES * sizeof(int));       // 12.8 MB

  wt_kernel<<<(IN_FEAT * OUT_FEAT) / 256, 256, 0, stream>>>(W, Wt);
  gemm_hist_kernel<<<HIST_BLKS + 782, 256, 0, stream>>>(x, Wt, a, erow, h16, s_src, s_dst, G);
  scan1_kernel<<<SCAN_BLOCKS, 256, 0, stream>>>(G, scanG, bsum);
  scan3_kernel<<<SCAN_BLOCKS, 256, 0, stream>>>(scanG, bsum);
  partition_kernel<<<NBLK, 1024, 0, stream>>>(erow, ecol, scanG, packed);
  bucket_scatter_kernel<<<NB, 512, 0, stream>>>(packed, scanG, offs, scol);
  attn_kernel<<<N_NODES / 4, 256, 0, stream>>>(h16, s_src, s_dst, offs, scol, out);
}